// Round 11
// baseline (146.421 us; speedup 1.0000x reference)
//
#include <hip/hip_runtime.h>
#include <hip/hip_fp16.h>
#include <math.h>

#define D 128
#define NPB 8
#define EPS1 (1.0f + 1e-6f)

// ---- DPP row_ror sum over each 16-lane row: all lanes get the total ----
__device__ __forceinline__ float dpp_rsum16(float v) {
    v += __int_as_float(__builtin_amdgcn_update_dpp(
        0, __float_as_int(v), 0x121, 0xf, 0xf, true));  // ror:1
    v += __int_as_float(__builtin_amdgcn_update_dpp(
        0, __float_as_int(v), 0x122, 0xf, 0xf, true));  // ror:2
    v += __int_as_float(__builtin_amdgcn_update_dpp(
        0, __float_as_int(v), 0x124, 0xf, 0xf, true));  // ror:4
    v += __int_as_float(__builtin_amdgcn_update_dpp(
        0, __float_as_int(v), 0x128, 0xf, 0xf, true));  // ror:8
    return v;
}

// fast acosh for a >= 1+1e-6
__device__ __forceinline__ float facosh(float a) {
    return __logf(a + sqrtf(fmaxf(a * a - 1.0f, 0.0f)));
}

__device__ __forceinline__ void unpack8(const float4& a, const float4& b,
                                        float* d) {
    d[0] = a.x; d[1] = a.y; d[2] = a.z; d[3] = a.w;
    d[4] = b.x; d[5] = b.y; d[6] = b.z; d[7] = b.w;
}

// 8 halfs packed in a float4 -> 8 floats
__device__ __forceinline__ void unpackh8(const float4& v, float* d) {
    const __half2* p = (const __half2*)&v;
#pragma unroll
    for (int t = 0; t < 4; t++) {
        float2 f = __half22float2(p[t]);
        d[2 * t] = f.x;
        d[2 * t + 1] = f.y;
    }
}

// ---------------------------------------------------------------------------
// Kernel 1: per-node pre-processing (512-thread k-split, unchanged from R10).
// Outputs: Xrow fp32, XQh fp16 (gather side x|Q), P fp32. Tail: histogram.
// ---------------------------------------------------------------------------
__device__ __forceinline__ void bsumH2(float* v, float (*wred)[2], int lane,
                                       int wid, int kp) {
    __syncthreads();
#pragma unroll
    for (int o = 32; o; o >>= 1)
#pragma unroll
        for (int nl = 0; nl < 2; nl++) v[nl] += __shfl_xor(v[nl], o, 64);
    if (lane == 0)
#pragma unroll
        for (int nl = 0; nl < 2; nl++) wred[wid][nl] = v[nl];
    __syncthreads();
#pragma unroll
    for (int nl = 0; nl < 2; nl++)
        v[nl] = wred[2 * kp][nl] + wred[2 * kp + 1][nl];
}

__global__ __launch_bounds__(512) void node_pre8(
    const float* __restrict__ h, const float* __restrict__ W,
    const float* __restrict__ bias, const float* __restrict__ att_w1,
    const float* __restrict__ att_b1, float* __restrict__ Xrow,
    __half* __restrict__ XQh, float* __restrict__ P_out,
    const int* __restrict__ row, int* __restrict__ cnt, int N, int E) {
    int i0 = blockIdx.x * NPB;
    int tid = threadIdx.x;
    int j = tid & 127, kp = tid >> 7;
    int lane = tid & 63, wid = tid >> 6;
    int nbase = kp * 2;
    __shared__ __align__(16) float t8[NPB][D];
    __shared__ float psumP[4][NPB][D];
    __shared__ float psumQ[4][NPB][D];
    __shared__ float wred[8][2];

    float hj[2];
#pragma unroll
    for (int nl = 0; nl < 2; nl++) {
        int gi = i0 + nbase + nl;
        hj[nl] = (gi < N) ? h[(size_t)gi * D + j] : 0.0f;
        t8[nbase + nl][j] = hj[nl];
    }
    __syncthreads();
    float tj[2];
#pragma unroll
    for (int nl = 0; nl < 2; nl++) {
        float h0 = fmaxf(t8[nbase + nl][0], EPS1);
        float fac = facosh(h0) * rsqrtf(h0 * h0 - 1.0f);
        tj[nl] = (j == 0) ? 0.0f : hj[nl] * fac;
    }
    __syncthreads();
#pragma unroll
    for (int nl = 0; nl < 2; nl++) t8[nbase + nl][j] = tj[nl];
    __syncthreads();

    float xtp[NPB];
#pragma unroll
    for (int n = 0; n < NPB; n++) xtp[n] = 0.0f;
    int kbeg = kp * 32;
    for (int k0 = kbeg; k0 < kbeg + 32; k0 += 4) {
        float w0 = W[(k0 + 0) * D + j], w1 = W[(k0 + 1) * D + j];
        float w2 = W[(k0 + 2) * D + j], w3 = W[(k0 + 3) * D + j];
#pragma unroll
        for (int n = 0; n < NPB; n++) {
            float4 tv = *(const float4*)&t8[n][k0];
            xtp[n] = fmaf(tv.x, w0,
                          fmaf(tv.y, w1, fmaf(tv.z, w2, fmaf(tv.w, w3, xtp[n]))));
        }
    }
#pragma unroll
    for (int n = 0; n < NPB; n++) psumP[kp][n][j] = xtp[n];
    __syncthreads();
    float xt[2];
#pragma unroll
    for (int nl = 0; nl < 2; nl++) {
        int n = nbase + nl;
        xt[nl] = (j == 0) ? 0.0f
                          : (psumP[0][n][j] + psumP[1][n][j] + psumP[2][n][j] +
                             psumP[3][n][j]);
    }

    float v2[2];
#pragma unroll
    for (int nl = 0; nl < 2; nl++) v2[nl] = xt[nl] * xt[nl];
    bsumH2(v2, wred, lane, wid, kp);
    float xj[2];
#pragma unroll
    for (int nl = 0; nl < 2; nl++) {
        float nn = sqrtf(fmaxf(v2[nl], 1e-6f));
        float e = __expf(nn), ei = __fdividef(1.0f, e);
        float ch = 0.5f * (e + ei), sh = 0.5f * (e - ei);
        xj[nl] = (j == 0) ? ch : __fdividef(sh, nn) * xt[nl];
    }

    float vj = (j == 0) ? 0.0f : bias[j];
#pragma unroll
    for (int nl = 0; nl < 2; nl++) v2[nl] = xj[nl] * vj;
    bsumH2(v2, wred, lane, wid, kp);
    __syncthreads();
#pragma unroll
    for (int nl = 0; nl < 2; nl++) t8[nbase + nl][j] = xj[nl];
    __syncthreads();
    float bj[2];
#pragma unroll
    for (int nl = 0; nl < 2; nl++) {
        float X0 = t8[nbase + nl][0];
        float coef = __fdividef(v2[nl], 1.0f + X0);
        bj[nl] = vj + coef * ((j == 0) ? (X0 + 1.0f) : xj[nl]);
    }
#pragma unroll
    for (int nl = 0; nl < 2; nl++)
        v2[nl] = (j == 0) ? -bj[nl] * bj[nl] : bj[nl] * bj[nl];
    bsumH2(v2, wred, lane, wid, kp);
    float xnj[2];
#pragma unroll
    for (int nl = 0; nl < 2; nl++) {
        float nb = sqrtf(fmaxf(v2[nl], 1e-6f));
        float e = __expf(nb), ei = __fdividef(1.0f, e);
        float ch = 0.5f * (e + ei), sh = 0.5f * (e - ei);
        xnj[nl] = ch * xj[nl] + __fdividef(sh, nb) * bj[nl];
        int gi = i0 + nbase + nl;
        if (gi < N) {
            Xrow[(size_t)gi * D + j] = xnj[nl];
            XQh[(size_t)gi * 256 + j] = __float2half(xnj[nl]);
        }
    }

    __syncthreads();
#pragma unroll
    for (int nl = 0; nl < 2; nl++) t8[nbase + nl][j] = xnj[nl];
    __syncthreads();
    float xtj[2];
#pragma unroll
    for (int nl = 0; nl < 2; nl++) {
        float Y0 = fmaxf(t8[nbase + nl][0], EPS1);
        float f = facosh(Y0) * rsqrtf(Y0 * Y0 - 1.0f);
        xtj[nl] = (j == 0) ? 0.0f : xnj[nl] * f;
    }
    __syncthreads();
#pragma unroll
    for (int nl = 0; nl < 2; nl++) t8[nbase + nl][j] = xtj[nl];
    __syncthreads();

    float pp[NPB], qq[NPB];
#pragma unroll
    for (int n = 0; n < NPB; n++) {
        pp[n] = 0.0f;
        qq[n] = 0.0f;
    }
    for (int k0 = kbeg; k0 < kbeg + 32; k0 += 4) {
        float a0 = att_w1[(k0 + 0) * D + j], a1 = att_w1[(k0 + 1) * D + j];
        float a2 = att_w1[(k0 + 2) * D + j], a3 = att_w1[(k0 + 3) * D + j];
        float c0 = att_w1[(D + k0 + 0) * D + j], c1 = att_w1[(D + k0 + 1) * D + j];
        float c2 = att_w1[(D + k0 + 2) * D + j], c3 = att_w1[(D + k0 + 3) * D + j];
#pragma unroll
        for (int n = 0; n < NPB; n++) {
            float4 tv = *(const float4*)&t8[n][k0];
            pp[n] = fmaf(tv.x, a0,
                         fmaf(tv.y, a1, fmaf(tv.z, a2, fmaf(tv.w, a3, pp[n]))));
            qq[n] = fmaf(tv.x, c0,
                         fmaf(tv.y, c1, fmaf(tv.z, c2, fmaf(tv.w, c3, qq[n]))));
        }
    }
#pragma unroll
    for (int n = 0; n < NPB; n++) {
        psumP[kp][n][j] = pp[n];
        psumQ[kp][n][j] = qq[n];
    }
    __syncthreads();
    float b1 = att_b1[j];
#pragma unroll
    for (int nl = 0; nl < 2; nl++) {
        int n = nbase + nl;
        int gi = i0 + n;
        if (gi < N) {
            P_out[(size_t)gi * D + j] = psumP[0][n][j] + psumP[1][n][j] +
                                        psumP[2][n][j] + psumP[3][n][j] + b1;
            float q = psumQ[0][n][j] + psumQ[1][n][j] + psumQ[2][n][j] +
                      psumQ[3][n][j];
            XQh[(size_t)gi * 256 + 128 + j] = __float2half(q);
        }
    }

    int gtid = blockIdx.x * 512 + tid;
    int tot = gridDim.x * 512;
    for (int e2 = gtid; e2 < E; e2 += tot) atomicAdd(&cnt[row[e2]], 1);
}

// ---------------------------------------------------------------------------
// CSR build: one-pass scan + scatter (unchanged)
// ---------------------------------------------------------------------------
__global__ __launch_bounds__(1024) void scan_kernel(const int* __restrict__ cnt,
                                                    int* __restrict__ off,
                                                    int* __restrict__ cursor,
                                                    int N) {
    __shared__ int wt[16];
    int tid = threadIdx.x, lane = tid & 63, wid = tid >> 6;
    int PER = (N + 1023) >> 10;
    int basei = tid * PER;
    int loc[16];
    int tsum = 0;
#pragma unroll 4
    for (int r = 0; r < PER; r++) {
        int idx = basei + r;
        int v = (idx < N) ? cnt[idx] : 0;
        loc[r] = tsum;
        tsum += v;
    }
    int inc = tsum;
#pragma unroll
    for (int o = 1; o < 64; o <<= 1) {
        int t = __shfl_up(inc, o, 64);
        if (lane >= o) inc += t;
    }
    if (lane == 63) wt[wid] = inc;
    __syncthreads();
    if (tid < 16) {
        int w = wt[tid];
#pragma unroll
        for (int o = 1; o < 16; o <<= 1) {
            int t = __shfl_up(w, o, 64);
            if ((tid & 15) >= o) w += t;
        }
        wt[tid] = w;
    }
    __syncthreads();
    int wbase = (wid == 0) ? 0 : wt[wid - 1];
    int texcl = wbase + inc - tsum;
    for (int r = 0; r < PER; r++) {
        int idx = basei + r;
        if (idx < N) {
            int o = texcl + loc[r];
            off[idx] = o;
            cursor[idx] = o;
        }
    }
}

__global__ void scatter_kernel(const int* __restrict__ row,
                               const int* __restrict__ col,
                               const float* __restrict__ edge_attr,
                               const float* __restrict__ edge_mask,
                               int* __restrict__ cursor,
                               float4* __restrict__ rec, int E) {
    const float2* ea2 = (const float2*)edge_attr;
    for (int e = blockIdx.x * blockDim.x + threadIdx.x; e < E;
         e += gridDim.x * blockDim.x) {
        int r = row[e];
        int pos = atomicAdd(&cursor[r], 1);
        float2 a = ea2[e];
        rec[pos] = make_float4(__int_as_float(col[e]), a.x, a.y, edge_mask[e]);
    }
}

// ---------------------------------------------------------------------------
// Kernel D: edge aggregation. TWO waves per node; 8 chunks (4 groups x 2
// waves). Chunk rec records preloaded into lane registers (one coalesced
// load), col/ea/mask broadcast via shfl -> gather addresses known upfront;
// gathers issued TWO computes ahead (depth-3 rotating fp16 buffers).
// Partials -> aggP[2i+w]; epilogue in node_post. No LDS, no atomics.
// ---------------------------------------------------------------------------
__global__ __launch_bounds__(256) void edge_agg(
    const float* __restrict__ Xrow, const float* __restrict__ P,
    const __half* __restrict__ XQh, const float4* __restrict__ rec,
    const int* __restrict__ off, const int* __restrict__ cnt,
    const float* __restrict__ w1c, const float* __restrict__ att_w2,
    const float* __restrict__ att_b2, float* __restrict__ aggP, int N) {
    int tid = threadIdx.x, lane = tid & 63, wid = tid >> 6;
    int sub = lane & 15, grp = lane >> 4, gb = lane & 48;
    int i = blockIdx.x * 2 + (wid >> 1);  // 2 waves per node
    int w = wid & 1;
    bool valid = i < N;
    i = min(i, N - 1);
    int f4 = sub * 2;

    const float4* w4 = (const float4*)w1c;
    const float4* aw4 = (const float4*)att_w2;
    const float4* xr4 = (const float4*)(Xrow + (size_t)i * D);
    const float4* pr4 = (const float4*)(P + (size_t)i * D);
    float xr[8], pr[8], wa[8], wb[8], wg[8], w2v[8];
    unpack8(xr4[f4], xr4[f4 + 1], xr);
    unpack8(pr4[f4], pr4[f4 + 1], pr);
    unpack8(w4[f4], w4[f4 + 1], wa);
    unpack8(w4[32 + f4], w4[32 + f4 + 1], wb);
    unpack8(w4[64 + f4], w4[64 + f4 + 1], wg);
    unpack8(aw4[f4], aw4[f4 + 1], w2v);
    float b2 = att_b2[0];
    float xr0s = (sub == 0) ? -xr[0] : xr[0];

    float acc[8];
#pragma unroll
    for (int u = 0; u < 8; u++) acc[u] = 0.0f;

    int s = off[i], m = valid ? cnt[i] : 0;
    int clen = (m + 7) >> 3;                 // 8 chunks per node
    int base = (w * 4 + grp) * clen;
    int len = min(m - base, clen);
    if (len < 0) len = 0;

    // preload this chunk's rec records (first 16) into lane registers
    float4 rp = make_float4(__int_as_float(0), 0.0f, 0.0f, 0.0f);
    if (sub < len) rp = rec[s + base + sub];
    int colp = __float_as_int(rp.x);

    auto computeE = [&](float eay, float eaz, float msk, bool act,
                        const float4& g0, const float4& g1) {
        float xc[8], qc[8];
        unpackh8(g0, xc);
        unpackh8(g1, qc);
        float lin = xr0s * xc[0];
#pragma unroll
        for (int u = 1; u < 8; u++) lin = fmaf(xr[u], xc[u], lin);
        lin = dpp_rsum16(lin);
        float alpha = fmaxf(-lin, EPS1);
        float a2m = fmaxf(fmaf(alpha, alpha, -1.0f), 1e-12f);
        float rden = rsqrtf(a2m);
        float geo = __logf(fmaf(a2m, rden, alpha));  // acosh(alpha)
        float lp = 0.0f;
#pragma unroll
        for (int u = 0; u < 8; u++) {
            float hv = pr[u] + qc[u] +
                       fmaf(eay, wa[u], fmaf(eaz, wb[u], geo * wg[u]));
            float sig = __fdividef(1.0f, 1.0f + __expf(-hv));
            lp = fmaf(hv * sig, w2v[u], lp);  // silu(h)*w2
        }
        lp = dpp_rsum16(lp);
        float wq = act ? msk : 0.0f;
        float att = wq * __fdividef(1.0f, 1.0f + __expf(-(lp + b2)));
        float scale = att * geo * rden * 1e-3f;
#pragma unroll
        for (int u = 0; u < 8; u++)
            acc[u] = fmaf(scale, fmaf(-alpha, xr[u], xc[u]), acc[u]);
    };

    int tmax = min(clen, 16);

    // ---- pipelined main loop: addresses known upfront, gathers 2 ahead ----
    {
        int c0 = __shfl(colp, gb | 0, 64);
        const float4* p0 = (const float4*)(XQh + (size_t)c0 * 256);
        float4 gA0 = p0[sub], gA1 = p0[16 + sub];
        int c1 = __shfl(colp, gb | 1, 64);
        const float4* p1 = (const float4*)(XQh + (size_t)c1 * 256);
        float4 gB0 = p1[sub], gB1 = p1[16 + sub];
        float4 gC0, gC1;

        for (int t = 0; t < tmax; ++t) {
            int cn = __shfl(colp, gb | ((t + 2) & 15), 64);
            const float4* pn = (const float4*)(XQh + (size_t)cn * 256);
            gC0 = pn[sub];
            gC1 = pn[16 + sub];
            float eay = __shfl(rp.y, gb | t, 64);
            float eaz = __shfl(rp.z, gb | t, 64);
            float msk = __shfl(rp.w, gb | t, 64);
            computeE(eay, eaz, msk, t < len, gA0, gA1);
            gA0 = gB0; gA1 = gB1;
            gB0 = gC0; gB1 = gC1;
        }
    }
    // ---- rare tail (m > 128): direct, unpipelined ----
    for (int t = 16; t < clen; ++t) {
        bool act = t < len;
        float4 rc = make_float4(__int_as_float(0), 0.0f, 0.0f, 0.0f);
        if (act) rc = rec[s + base + t];
        const float4* pt =
            (const float4*)(XQh + (size_t)__float_as_int(rc.x) * 256);
        float4 g0 = pt[sub], g1 = pt[16 + sub];
        computeE(rc.y, rc.z, rc.w, act, g0, g1);
    }

    // merge this wave's 4 chunk-partials; grp 0 stores the wave partial
#pragma unroll
    for (int u = 0; u < 8; u++) {
        acc[u] += __shfl_xor(acc[u], 16, 64);
        acc[u] += __shfl_xor(acc[u], 32, 64);
    }
    if (valid && grp == 0) {
        float4* a4 = (float4*)(aggP + (size_t)(2 * i + w) * D);
        a4[f4] = make_float4(acc[0], acc[1], acc[2], acc[3]);
        a4[f4 + 1] = make_float4(acc[4], acc[5], acc[6], acc[7]);
    }
}

// ---------------------------------------------------------------------------
// Kernel E: per-node epilogue, 16-lane group per node, register-only.
// Sums the two wave-partials from aggP.
// ---------------------------------------------------------------------------
__global__ __launch_bounds__(256) void node_post(
    const float* __restrict__ Xrow, const float* __restrict__ aggP,
    const float* __restrict__ gamma, const float* __restrict__ beta,
    float* __restrict__ out, int N) {
    int tid = threadIdx.x, lane = tid & 63;
    int sub = lane & 15;
    int i = blockIdx.x * 16 + (tid >> 4);
    bool valid = i < N;
    i = min(i, N - 1);
    int j8 = sub * 8, f4 = sub * 2;

    const float4* xr4 = (const float4*)(Xrow + (size_t)i * D);
    const float4* a4a = (const float4*)(aggP + (size_t)(2 * i) * D);
    const float4* a4b = (const float4*)(aggP + (size_t)(2 * i + 1) * D);
    float xr[8], p0[8], p1[8], acc[8];
    unpack8(xr4[f4], xr4[f4 + 1], xr);
    unpack8(a4a[f4], a4a[f4 + 1], p0);
    unpack8(a4b[f4], a4b[f4 + 1], p1);
#pragma unroll
    for (int u = 0; u < 8; u++) acc[u] = p0[u] + p1[u];

    float lxa_p = (sub == 0) ? -xr[0] * acc[0] : xr[0] * acc[0];
#pragma unroll
    for (int u = 1; u < 8; u++) lxa_p = fmaf(xr[u], acc[u], lxa_p);
    float lxa = dpp_rsum16(lxa_p);
    float uj[8];
#pragma unroll
    for (int u = 0; u < 8; u++) uj[u] = fmaf(lxa, xr[u], acc[u]);
    float luu_p = (sub == 0) ? -uj[0] * uj[0] : uj[0] * uj[0];
#pragma unroll
    for (int u = 1; u < 8; u++) luu_p = fmaf(uj[u], uj[u], luu_p);
    float luu = dpp_rsum16(luu_p);
    float nn = sqrtf(fmaxf(luu, 1e-6f));
    float e = __expf(nn), ei = __fdividef(1.0f, e);
    float ch = 0.5f * (e + ei), shv = __fdividef(0.5f * (e - ei), nn);
    float xn[8];
#pragma unroll
    for (int u = 0; u < 8; u++) xn[u] = ch * xr[u] + shv * uj[u];
    float X0 = __shfl(xn[0], lane & 48, 64);
    X0 = fmaxf(X0, EPS1);
    float fc = facosh(X0) * rsqrtf(X0 * X0 - 1.0f);
    float ht[8];
#pragma unroll
    for (int u = 0; u < 8; u++) ht[u] = xn[u] * fc;
    if (sub == 0) ht[0] = 0.0f;
    float mp = 0.0f;
#pragma unroll
    for (int u = 0; u < 8; u++) mp += ht[u];
    float mean = dpp_rsum16(mp) * (1.0f / 127.0f);
    float diff[8];
#pragma unroll
    for (int u = 0; u < 8; u++) diff[u] = ht[u] - mean;
    if (sub == 0) diff[0] = 0.0f;
    float vp = 0.0f;
#pragma unroll
    for (int u = 0; u < 8; u++) vp = fmaf(diff[u], diff[u], vp);
    float var = dpp_rsum16(vp) * (1.0f / 127.0f);
    float rstd = rsqrtf(var + 1e-5f);
    float sp[8];
#pragma unroll
    for (int u = 0; u < 8; u++) {
        int j = j8 + u;
        float g = (j > 0) ? gamma[j - 1] : 0.0f;
        float bt = (j > 0) ? beta[j - 1] : 0.0f;
        sp[u] = fmaf(diff[u] * rstd, g, bt);
    }
    if (sub == 0) sp[0] = 0.0f;
    float n2p = 0.0f;
#pragma unroll
    for (int u = 0; u < 8; u++) n2p = fmaf(sp[u], sp[u], n2p);
    float n2 = sqrtf(fmaxf(dpp_rsum16(n2p), 1e-6f));
    e = __expf(n2);
    ei = __fdividef(1.0f, e);
    float y0 = 0.5f * (e + ei), sh2 = __fdividef(0.5f * (e - ei), n2);
    float yj[8];
#pragma unroll
    for (int u = 0; u < 8; u++) yj[u] = sh2 * sp[u];
    if (sub == 0) yj[0] = y0;
    float y0c = fmaxf(y0, EPS1);
    float f3 = facosh(y0c) * rsqrtf(y0c * y0c - 1.0f);
    float sj[8];
#pragma unroll
    for (int u = 0; u < 8; u++) {
        float lj = yj[u] * f3;
        sj[u] = __fdividef(lj, 1.0f + __expf(-lj));
    }
    if (sub == 0) sj[0] = 0.0f;
    float n3p = 0.0f;
#pragma unroll
    for (int u = 0; u < 8; u++) n3p = fmaf(sj[u], sj[u], n3p);
    float n3 = sqrtf(fmaxf(dpp_rsum16(n3p), 1e-6f));
    e = __expf(n3);
    ei = __fdividef(1.0f, e);
    float o0 = 0.5f * (e + ei), sh3 = __fdividef(0.5f * (e - ei), n3);
    float ov[8];
#pragma unroll
    for (int u = 0; u < 8; u++) ov[u] = sh3 * sj[u];
    if (sub == 0) ov[0] = o0;
    if (valid) {
        float4* o4 = (float4*)(out + (size_t)i * D);
        o4[f4] = make_float4(ov[0], ov[1], ov[2], ov[3]);
        o4[f4 + 1] = make_float4(ov[4], ov[5], ov[6], ov[7]);
    }
}

extern "C" void kernel_launch(void* const* d_in, const int* in_sizes, int n_in,
                              void* d_out, int out_size, void* d_ws,
                              size_t ws_size, hipStream_t stream) {
    const float* h = (const float*)d_in[0];
    const float* edge_attr = (const float*)d_in[1];
    const int* row = (const int*)d_in[2];
    const int* col = (const int*)d_in[3];
    const float* edge_mask = (const float*)d_in[5];
    const float* W = (const float*)d_in[6];
    const float* bias = (const float*)d_in[7];
    const float* att_w1 = (const float*)d_in[8];
    const float* att_b1 = (const float*)d_in[9];
    const float* att_w2 = (const float*)d_in[10];
    const float* att_b2 = (const float*)d_in[11];
    const float* ln_g = (const float*)d_in[12];
    const float* ln_b = (const float*)d_in[13];

    int N = in_sizes[0] / D;
    int E = in_sizes[2];

    float* Xrow = (float*)d_ws;                      // N*128 fp32
    float* Pbuf = Xrow + (size_t)N * D;              // N*128 fp32
    __half* XQh = (__half*)(Pbuf + (size_t)N * D);   // N*256 fp16
    float4* rec = (float4*)(XQh + (size_t)N * 256);  // E recs
    int* cnt = (int*)(rec + E);
    int* off = cnt + N;
    int* cur = off + N;
    float* aggP = (float*)(cur + N);                 // N*2*128 fp32 partials

    hipMemsetAsync(cnt, 0, N * sizeof(int), stream);
    node_pre8<<<(N + NPB - 1) / NPB, 512, 0, stream>>>(
        h, W, bias, att_w1, att_b1, Xrow, XQh, Pbuf, row, cnt, N, E);
    scan_kernel<<<1, 1024, 0, stream>>>(cnt, off, cur, N);
    scatter_kernel<<<640, 256, 0, stream>>>(row, col, edge_attr, edge_mask,
                                            cur, rec, E);
    edge_agg<<<(N + 1) / 2, 256, 0, stream>>>(Xrow, Pbuf, XQh, rec, off, cnt,
                                              att_w1 + 256 * D, att_w2,
                                              att_b2, aggP, N);
    node_post<<<(N + 15) / 16, 256, 0, stream>>>(Xrow, aggP, ln_g, ln_b,
                                                 (float*)d_out, N);
}

// Round 13
// 140.176 us; speedup vs baseline: 1.0446x; 1.0446x over previous
//
#include <hip/hip_runtime.h>
#include <hip/hip_fp16.h>
#include <math.h>

#define D 128
#define EPS1 (1.0f + 1e-6f)

// ---- DPP row_ror sum over each 16-lane row: all lanes get the total ----
__device__ __forceinline__ float dpp_rsum16(float v) {
    v += __int_as_float(__builtin_amdgcn_update_dpp(
        0, __float_as_int(v), 0x121, 0xf, 0xf, true));  // ror:1
    v += __int_as_float(__builtin_amdgcn_update_dpp(
        0, __float_as_int(v), 0x122, 0xf, 0xf, true));  // ror:2
    v += __int_as_float(__builtin_amdgcn_update_dpp(
        0, __float_as_int(v), 0x124, 0xf, 0xf, true));  // ror:4
    v += __int_as_float(__builtin_amdgcn_update_dpp(
        0, __float_as_int(v), 0x128, 0xf, 0xf, true));  // ror:8
    return v;
}

// full 64-lane sum, all lanes get the total
__device__ __forceinline__ float wsum64(float v) {
    v = dpp_rsum16(v);
    v += __shfl_xor(v, 16, 64);
    v += __shfl_xor(v, 32, 64);
    return v;
}

// fast acosh for a >= 1+1e-6
__device__ __forceinline__ float facosh(float a) {
    return __logf(a + sqrtf(fmaxf(a * a - 1.0f, 0.0f)));
}

__device__ __forceinline__ void unpack8(const float4& a, const float4& b,
                                        float* d) {
    d[0] = a.x; d[1] = a.y; d[2] = a.z; d[3] = a.w;
    d[4] = b.x; d[5] = b.y; d[6] = b.z; d[7] = b.w;
}

// 8 halfs packed in a float4 -> 8 floats
__device__ __forceinline__ void unpackh8(const float4& v, float* d) {
    const __half2* p = (const __half2*)&v;
#pragma unroll
    for (int t = 0; t < 4; t++) {
        float2 f = __half22float2(p[t]);
        d[2 * t] = f.x;
        d[2 * t + 1] = f.y;
    }
}

// ---------------------------------------------------------------------------
// hist: grid-stride histogram of row into cnt
// ---------------------------------------------------------------------------
__global__ void hist_kernel(const int* __restrict__ row, int* __restrict__ cnt,
                            int E) {
    for (int e = blockIdx.x * blockDim.x + threadIdx.x; e < E;
         e += gridDim.x * blockDim.x)
        atomicAdd(&cnt[row[e]], 1);
}

// ---------------------------------------------------------------------------
// scan: one-pass single-block exclusive scan
// ---------------------------------------------------------------------------
__global__ __launch_bounds__(1024) void scan_kernel(const int* __restrict__ cnt,
                                                    int* __restrict__ off,
                                                    int* __restrict__ cursor,
                                                    int N) {
    __shared__ int wt[16];
    int tid = threadIdx.x, lane = tid & 63, wid = tid >> 6;
    int PER = (N + 1023) >> 10;
    int basei = tid * PER;
    int loc[16];
    int tsum = 0;
#pragma unroll 4
    for (int r = 0; r < PER; r++) {
        int idx = basei + r;
        int v = (idx < N) ? cnt[idx] : 0;
        loc[r] = tsum;
        tsum += v;
    }
    int inc = tsum;
#pragma unroll
    for (int o = 1; o < 64; o <<= 1) {
        int t = __shfl_up(inc, o, 64);
        if (lane >= o) inc += t;
    }
    if (lane == 63) wt[wid] = inc;
    __syncthreads();
    if (tid < 16) {
        int w = wt[tid];
#pragma unroll
        for (int o = 1; o < 16; o <<= 1) {
            int t = __shfl_up(w, o, 64);
            if ((tid & 15) >= o) w += t;
        }
        wt[tid] = w;
    }
    __syncthreads();
    int wbase = (wid == 0) ? 0 : wt[wid - 1];
    int texcl = wbase + inc - tsum;
    for (int r = 0; r < PER; r++) {
        int idx = basei + r;
        if (idx < N) {
            int o = texcl + loc[r];
            off[idx] = o;
            cursor[idx] = o;
        }
    }
}

// ---------------------------------------------------------------------------
// Kernel 1 v3: per-node pre-processing, 4 barriers total.
// 512 threads = 8 waves; block owns 8 nodes; WAVE wv OWNS NODE i0+wv
// (one node per wave — t8[8] capacity == nodes/block, fixes R12 OOB).
// Matmuls: (j=tid&127, kp=tid>>7) k-split, LDS psum (W read once/block).
// Elementwise: wave-local, lane covers j0=2*lane, j0+1; reductions via
// in-register DPP wsum64 (no LDS, no barriers).
// Tail: grid-stride scatter (cursor ready: scan runs before this kernel).
// ---------------------------------------------------------------------------
__global__ __launch_bounds__(512) void node_pre8(
    const float* __restrict__ h, const float* __restrict__ W,
    const float* __restrict__ bias, const float* __restrict__ att_w1,
    const float* __restrict__ att_b1, float* __restrict__ Xrow,
    __half* __restrict__ XQh, float* __restrict__ P_out,
    const int* __restrict__ row, const int* __restrict__ col,
    const float* __restrict__ edge_attr, const float* __restrict__ edge_mask,
    int* __restrict__ cursor, float4* __restrict__ rec, int N, int E) {
    int i0 = blockIdx.x * 8;
    int tid = threadIdx.x;
    int j = tid & 127, kp = tid >> 7;    // matmul mapping (4 k-quarters)
    int lane = tid & 63, wv = tid >> 6;  // 8 waves; wave wv owns node i0+wv
    int j0 = 2 * lane;
    __shared__ __align__(16) float t8[8][D];
    __shared__ float psP[4][8][D];
    __shared__ float psQ[4][8][D];

    bool vA = (i0 + wv) < N;
    size_t gA = min(i0 + wv, N - 1);

    // ---- Phase A: logmap0(h) for own node -> t8[wv] ----
    float2 hA = *(const float2*)&h[gA * D + j0];
    float h0A = fmaxf(__shfl(hA.x, 0, 64), EPS1);
    float facA = facosh(h0A) * rsqrtf(h0A * h0A - 1.0f);
    float tax = (lane == 0) ? 0.0f : hA.x * facA;
    float tay = hA.y * facA;
    *(float2*)&t8[wv][j0] = make_float2(tax, tay);
    __syncthreads();  // B1

    // ---- Phase B: xt partials over k-quarter, all 8 nodes ----
    {
        float xtp[8];
#pragma unroll
        for (int n = 0; n < 8; n++) xtp[n] = 0.0f;
        int kbeg = kp * 32;
        for (int k0 = kbeg; k0 < kbeg + 32; k0 += 4) {
            float w0 = W[(k0 + 0) * D + j], w1 = W[(k0 + 1) * D + j];
            float w2 = W[(k0 + 2) * D + j], w3 = W[(k0 + 3) * D + j];
#pragma unroll
            for (int n = 0; n < 8; n++) {
                float4 tv = *(const float4*)&t8[n][k0];
                xtp[n] = fmaf(
                    tv.x, w0,
                    fmaf(tv.y, w1, fmaf(tv.z, w2, fmaf(tv.w, w3, xtp[n]))));
            }
        }
#pragma unroll
        for (int n = 0; n < 8; n++) psP[kp][n][j] = xtp[n];
    }
    __syncthreads();  // B2

    // ---- Phase C: wave-local elementwise chain for own node ----
    float xnax, xnay;
    {
        float2 a0 = *(const float2*)&psP[0][wv][j0];
        float2 a1 = *(const float2*)&psP[1][wv][j0];
        float2 a2 = *(const float2*)&psP[2][wv][j0];
        float2 a3 = *(const float2*)&psP[3][wv][j0];
        float xtax = a0.x + a1.x + a2.x + a3.x;
        float xtay = a0.y + a1.y + a2.y + a3.y;
        if (lane == 0) xtax = 0.0f;

        // expmap0
        float nsqA = wsum64(xtax * xtax + xtay * xtay);
        float nnA = sqrtf(fmaxf(nsqA, 1e-6f));
        float eA = __expf(nnA), eiA = __fdividef(1.0f, eA);
        float chA = 0.5f * (eA + eiA), shA = __fdividef(0.5f * (eA - eiA), nnA);
        float xax = (lane == 0) ? chA : shA * xtax;
        float xay = shA * xtay;

        // b = transp0(x, [0,bias]); xn = expmap(x, b)
        float2 bv = *(const float2*)&bias[j0];
        float va = (lane == 0) ? 0.0f : bv.x, vb = bv.y;
        float lxvA = wsum64(xax * va + xay * vb);
        float coefA = __fdividef(lxvA, 1.0f + chA);
        float baA = (lane == 0) ? coefA * (chA + 1.0f) : fmaf(coefA, xax, va);
        float bbA = fmaf(coefA, xay, vb);
        float lbbA = wsum64(((lane == 0) ? -baA * baA : baA * baA) + bbA * bbA);
        float nbA = sqrtf(fmaxf(lbbA, 1e-6f));
        float e2A = __expf(nbA), ei2A = __fdividef(1.0f, e2A);
        float ch2A = 0.5f * (e2A + ei2A);
        float sh2A = __fdividef(0.5f * (e2A - ei2A), nbA);
        xnax = ch2A * xax + sh2A * baA;
        xnay = ch2A * xay + sh2A * bbA;
        if (vA) {
            *(float2*)&Xrow[gA * D + j0] = make_float2(xnax, xnay);
            *(__half2*)&XQh[gA * 256 + j0] =
                __float22half2_rn(make_float2(xnax, xnay));
        }

        // x_tan = logmap0(xn) -> t8[wv]
        float Y0A = fmaxf(__shfl(xnax, 0, 64), EPS1);
        float fA = facosh(Y0A) * rsqrtf(Y0A * Y0A - 1.0f);
        float x2ax = (lane == 0) ? 0.0f : xnax * fA;
        float x2ay = xnay * fA;
        *(float2*)&t8[wv][j0] = make_float2(x2ax, x2ay);
    }
    __syncthreads();  // B3

    // ---- Phase D: P/Q partials over k-quarter, all 8 nodes ----
    {
        float pp[8], qq[8];
#pragma unroll
        for (int n = 0; n < 8; n++) {
            pp[n] = 0.0f;
            qq[n] = 0.0f;
        }
        int kbeg = kp * 32;
        for (int k0 = kbeg; k0 < kbeg + 32; k0 += 4) {
            float a0 = att_w1[(k0 + 0) * D + j], a1 = att_w1[(k0 + 1) * D + j];
            float a2 = att_w1[(k0 + 2) * D + j], a3 = att_w1[(k0 + 3) * D + j];
            float c0 = att_w1[(D + k0 + 0) * D + j];
            float c1 = att_w1[(D + k0 + 1) * D + j];
            float c2 = att_w1[(D + k0 + 2) * D + j];
            float c3 = att_w1[(D + k0 + 3) * D + j];
#pragma unroll
            for (int n = 0; n < 8; n++) {
                float4 tv = *(const float4*)&t8[n][k0];
                pp[n] = fmaf(
                    tv.x, a0,
                    fmaf(tv.y, a1, fmaf(tv.z, a2, fmaf(tv.w, a3, pp[n]))));
                qq[n] = fmaf(
                    tv.x, c0,
                    fmaf(tv.y, c1, fmaf(tv.z, c2, fmaf(tv.w, c3, qq[n]))));
            }
        }
#pragma unroll
        for (int n = 0; n < 8; n++) {
            psP[kp][n][j] = pp[n];
            psQ[kp][n][j] = qq[n];
        }
    }
    __syncthreads();  // B4

    // ---- Phase E: wave-local assembly + stores for own node ----
    if (vA) {
        float2 b1v = *(const float2*)&att_b1[j0];
        float2 a0 = *(const float2*)&psP[0][wv][j0];
        float2 a1 = *(const float2*)&psP[1][wv][j0];
        float2 a2 = *(const float2*)&psP[2][wv][j0];
        float2 a3 = *(const float2*)&psP[3][wv][j0];
        float2 q0 = *(const float2*)&psQ[0][wv][j0];
        float2 q1 = *(const float2*)&psQ[1][wv][j0];
        float2 q2 = *(const float2*)&psQ[2][wv][j0];
        float2 q3 = *(const float2*)&psQ[3][wv][j0];
        *(float2*)&P_out[gA * D + j0] =
            make_float2(a0.x + a1.x + a2.x + a3.x + b1v.x,
                        a0.y + a1.y + a2.y + a3.y + b1v.y);
        *(__half2*)&XQh[gA * 256 + 128 + j0] = __float22half2_rn(
            make_float2(q0.x + q1.x + q2.x + q3.x, q0.y + q1.y + q2.y + q3.y));
    }

    // ---- Tail: grid-stride scatter (cursor ready; hidden under latency) ----
    const float2* ea2 = (const float2*)edge_attr;
    int gtid = blockIdx.x * 512 + tid;
    int tot = gridDim.x * 512;
    for (int e = gtid; e < E; e += tot) {
        int r = row[e];
        int pos = atomicAdd(&cursor[r], 1);
        float2 a = ea2[e];
        rec[pos] = make_float4(__int_as_float(col[e]), a.x, a.y, edge_mask[e]);
    }
}

// ---------------------------------------------------------------------------
// Kernel D: edge aggregation (R11 structure, unchanged). TWO waves per node;
// 8 chunks; rec preloaded to lane registers; gathers 2 computes ahead.
// ---------------------------------------------------------------------------
__global__ __launch_bounds__(256) void edge_agg(
    const float* __restrict__ Xrow, const float* __restrict__ P,
    const __half* __restrict__ XQh, const float4* __restrict__ rec,
    const int* __restrict__ off, const int* __restrict__ cnt,
    const float* __restrict__ w1c, const float* __restrict__ att_w2,
    const float* __restrict__ att_b2, float* __restrict__ aggP, int N) {
    int tid = threadIdx.x, lane = tid & 63, wid = tid >> 6;
    int sub = lane & 15, grp = lane >> 4, gb = lane & 48;
    int i = blockIdx.x * 2 + (wid >> 1);
    int w = wid & 1;
    bool valid = i < N;
    i = min(i, N - 1);
    int f4 = sub * 2;

    const float4* w4 = (const float4*)w1c;
    const float4* aw4 = (const float4*)att_w2;
    const float4* xr4 = (const float4*)(Xrow + (size_t)i * D);
    const float4* pr4 = (const float4*)(P + (size_t)i * D);
    float xr[8], pr[8], wa[8], wb[8], wg[8], w2v[8];
    unpack8(xr4[f4], xr4[f4 + 1], xr);
    unpack8(pr4[f4], pr4[f4 + 1], pr);
    unpack8(w4[f4], w4[f4 + 1], wa);
    unpack8(w4[32 + f4], w4[32 + f4 + 1], wb);
    unpack8(w4[64 + f4], w4[64 + f4 + 1], wg);
    unpack8(aw4[f4], aw4[f4 + 1], w2v);
    float b2 = att_b2[0];
    float xr0s = (sub == 0) ? -xr[0] : xr[0];

    float acc[8];
#pragma unroll
    for (int u = 0; u < 8; u++) acc[u] = 0.0f;

    int s = off[i], m = valid ? cnt[i] : 0;
    int clen = (m + 7) >> 3;
    int base = (w * 4 + grp) * clen;
    int len = min(m - base, clen);
    if (len < 0) len = 0;

    float4 rp = make_float4(__int_as_float(0), 0.0f, 0.0f, 0.0f);
    if (sub < len) rp = rec[s + base + sub];
    int colp = __float_as_int(rp.x);

    auto computeE = [&](float eay, float eaz, float msk, bool act,
                        const float4& g0, const float4& g1) {
        float xc[8], qc[8];
        unpackh8(g0, xc);
        unpackh8(g1, qc);
        float lin = xr0s * xc[0];
#pragma unroll
        for (int u = 1; u < 8; u++) lin = fmaf(xr[u], xc[u], lin);
        lin = dpp_rsum16(lin);
        float alpha = fmaxf(-lin, EPS1);
        float a2m = fmaxf(fmaf(alpha, alpha, -1.0f), 1e-12f);
        float rden = rsqrtf(a2m);
        float geo = __logf(fmaf(a2m, rden, alpha));
        float lp = 0.0f;
#pragma unroll
        for (int u = 0; u < 8; u++) {
            float hv = pr[u] + qc[u] +
                       fmaf(eay, wa[u], fmaf(eaz, wb[u], geo * wg[u]));
            float sig = __fdividef(1.0f, 1.0f + __expf(-hv));
            lp = fmaf(hv * sig, w2v[u], lp);
        }
        lp = dpp_rsum16(lp);
        float wq = act ? msk : 0.0f;
        float att = wq * __fdividef(1.0f, 1.0f + __expf(-(lp + b2)));
        float scale = att * geo * rden * 1e-3f;
#pragma unroll
        for (int u = 0; u < 8; u++)
            acc[u] = fmaf(scale, fmaf(-alpha, xr[u], xc[u]), acc[u]);
    };

    int tmax = min(clen, 16);
    {
        int c0 = __shfl(colp, gb | 0, 64);
        const float4* p0 = (const float4*)(XQh + (size_t)c0 * 256);
        float4 gA0 = p0[sub], gA1 = p0[16 + sub];
        int c1 = __shfl(colp, gb | 1, 64);
        const float4* p1 = (const float4*)(XQh + (size_t)c1 * 256);
        float4 gB0 = p1[sub], gB1 = p1[16 + sub];
        float4 gC0, gC1;

        for (int t = 0; t < tmax; ++t) {
            int cn = __shfl(colp, gb | ((t + 2) & 15), 64);
            const float4* pn = (const float4*)(XQh + (size_t)cn * 256);
            gC0 = pn[sub];
            gC1 = pn[16 + sub];
            float eay = __shfl(rp.y, gb | t, 64);
            float eaz = __shfl(rp.z, gb | t, 64);
            float msk = __shfl(rp.w, gb | t, 64);
            computeE(eay, eaz, msk, t < len, gA0, gA1);
            gA0 = gB0; gA1 = gB1;
            gB0 = gC0; gB1 = gC1;
        }
    }
    for (int t = 16; t < clen; ++t) {
        bool act = t < len;
        float4 rc = make_float4(__int_as_float(0), 0.0f, 0.0f, 0.0f);
        if (act) rc = rec[s + base + t];
        const float4* pt =
            (const float4*)(XQh + (size_t)__float_as_int(rc.x) * 256);
        float4 g0 = pt[sub], g1 = pt[16 + sub];
        computeE(rc.y, rc.z, rc.w, act, g0, g1);
    }

#pragma unroll
    for (int u = 0; u < 8; u++) {
        acc[u] += __shfl_xor(acc[u], 16, 64);
        acc[u] += __shfl_xor(acc[u], 32, 64);
    }
    if (valid && grp == 0) {
        float4* a4 = (float4*)(aggP + (size_t)(2 * i + w) * D);
        a4[f4] = make_float4(acc[0], acc[1], acc[2], acc[3]);
        a4[f4 + 1] = make_float4(acc[4], acc[5], acc[6], acc[7]);
    }
}

// ---------------------------------------------------------------------------
// Kernel E: per-node epilogue (unchanged from R11).
// ---------------------------------------------------------------------------
__global__ __launch_bounds__(256) void node_post(
    const float* __restrict__ Xrow, const float* __restrict__ aggP,
    const float* __restrict__ gamma, const float* __restrict__ beta,
    float* __restrict__ out, int N) {
    int tid = threadIdx.x, lane = tid & 63;
    int sub = lane & 15;
    int i = blockIdx.x * 16 + (tid >> 4);
    bool valid = i < N;
    i = min(i, N - 1);
    int j8 = sub * 8, f4 = sub * 2;

    const float4* xr4 = (const float4*)(Xrow + (size_t)i * D);
    const float4* a4a = (const float4*)(aggP + (size_t)(2 * i) * D);
    const float4* a4b = (const float4*)(aggP + (size_t)(2 * i + 1) * D);
    float xr[8], p0[8], p1[8], acc[8];
    unpack8(xr4[f4], xr4[f4 + 1], xr);
    unpack8(a4a[f4], a4a[f4 + 1], p0);
    unpack8(a4b[f4], a4b[f4 + 1], p1);
#pragma unroll
    for (int u = 0; u < 8; u++) acc[u] = p0[u] + p1[u];

    float lxa_p = (sub == 0) ? -xr[0] * acc[0] : xr[0] * acc[0];
#pragma unroll
    for (int u = 1; u < 8; u++) lxa_p = fmaf(xr[u], acc[u], lxa_p);
    float lxa = dpp_rsum16(lxa_p);
    float uj[8];
#pragma unroll
    for (int u = 0; u < 8; u++) uj[u] = fmaf(lxa, xr[u], acc[u]);
    float luu_p = (sub == 0) ? -uj[0] * uj[0] : uj[0] * uj[0];
#pragma unroll
    for (int u = 1; u < 8; u++) luu_p = fmaf(uj[u], uj[u], luu_p);
    float luu = dpp_rsum16(luu_p);
    float nn = sqrtf(fmaxf(luu, 1e-6f));
    float e = __expf(nn), ei = __fdividef(1.0f, e);
    float ch = 0.5f * (e + ei), shv = __fdividef(0.5f * (e - ei), nn);
    float xn[8];
#pragma unroll
    for (int u = 0; u < 8; u++) xn[u] = ch * xr[u] + shv * uj[u];
    float X0 = __shfl(xn[0], lane & 48, 64);
    X0 = fmaxf(X0, EPS1);
    float fc = facosh(X0) * rsqrtf(X0 * X0 - 1.0f);
    float ht[8];
#pragma unroll
    for (int u = 0; u < 8; u++) ht[u] = xn[u] * fc;
    if (sub == 0) ht[0] = 0.0f;
    float mp = 0.0f;
#pragma unroll
    for (int u = 0; u < 8; u++) mp += ht[u];
    float mean = dpp_rsum16(mp) * (1.0f / 127.0f);
    float diff[8];
#pragma unroll
    for (int u = 0; u < 8; u++) diff[u] = ht[u] - mean;
    if (sub == 0) diff[0] = 0.0f;
    float vp = 0.0f;
#pragma unroll
    for (int u = 0; u < 8; u++) vp = fmaf(diff[u], diff[u], vp);
    float var = dpp_rsum16(vp) * (1.0f / 127.0f);
    float rstd = rsqrtf(var + 1e-5f);
    float sp[8];
#pragma unroll
    for (int u = 0; u < 8; u++) {
        int jj = j8 + u;
        float g = (jj > 0) ? gamma[jj - 1] : 0.0f;
        float bt = (jj > 0) ? beta[jj - 1] : 0.0f;
        sp[u] = fmaf(diff[u] * rstd, g, bt);
    }
    if (sub == 0) sp[0] = 0.0f;
    float n2p = 0.0f;
#pragma unroll
    for (int u = 0; u < 8; u++) n2p = fmaf(sp[u], sp[u], n2p);
    float n2 = sqrtf(fmaxf(dpp_rsum16(n2p), 1e-6f));
    e = __expf(n2);
    ei = __fdividef(1.0f, e);
    float y0 = 0.5f * (e + ei), sh2 = __fdividef(0.5f * (e - ei), n2);
    float yj[8];
#pragma unroll
    for (int u = 0; u < 8; u++) yj[u] = sh2 * sp[u];
    if (sub == 0) yj[0] = y0;
    float y0c = fmaxf(y0, EPS1);
    float f3 = facosh(y0c) * rsqrtf(y0c * y0c - 1.0f);
    float sj[8];
#pragma unroll
    for (int u = 0; u < 8; u++) {
        float lj = yj[u] * f3;
        sj[u] = __fdividef(lj, 1.0f + __expf(-lj));
    }
    if (sub == 0) sj[0] = 0.0f;
    float n3p = 0.0f;
#pragma unroll
    for (int u = 0; u < 8; u++) n3p = fmaf(sj[u], sj[u], n3p);
    float n3 = sqrtf(fmaxf(dpp_rsum16(n3p), 1e-6f));
    e = __expf(n3);
    ei = __fdividef(1.0f, e);
    float o0 = 0.5f * (e + ei), sh3 = __fdividef(0.5f * (e - ei), n3);
    float ov[8];
#pragma unroll
    for (int u = 0; u < 8; u++) ov[u] = sh3 * sj[u];
    if (sub == 0) ov[0] = o0;
    if (valid) {
        float4* o4 = (float4*)(out + (size_t)i * D);
        o4[f4] = make_float4(ov[0], ov[1], ov[2], ov[3]);
        o4[f4 + 1] = make_float4(ov[4], ov[5], ov[6], ov[7]);
    }
}

extern "C" void kernel_launch(void* const* d_in, const int* in_sizes, int n_in,
                              void* d_out, int out_size, void* d_ws,
                              size_t ws_size, hipStream_t stream) {
    const float* h = (const float*)d_in[0];
    const float* edge_attr = (const float*)d_in[1];
    const int* row = (const int*)d_in[2];
    const int* col = (const int*)d_in[3];
    const float* edge_mask = (const float*)d_in[5];
    const float* W = (const float*)d_in[6];
    const float* bias = (const float*)d_in[7];
    const float* att_w1 = (const float*)d_in[8];
    const float* att_b1 = (const float*)d_in[9];
    const float* att_w2 = (const float*)d_in[10];
    const float* att_b2 = (const float*)d_in[11];
    const float* ln_g = (const float*)d_in[12];
    const float* ln_b = (const float*)d_in[13];

    int N = in_sizes[0] / D;
    int E = in_sizes[2];

    float* Xrow = (float*)d_ws;                      // N*128 fp32
    float* Pbuf = Xrow + (size_t)N * D;              // N*128 fp32
    __half* XQh = (__half*)(Pbuf + (size_t)N * D);   // N*256 fp16
    float4* rec = (float4*)(XQh + (size_t)N * 256);  // E recs
    int* cnt = (int*)(rec + E);
    int* off = cnt + N;
    int* cur = off + N;
    float* aggP = (float*)(cur + N);                 // N*2*128 fp32 partials

    hipMemsetAsync(cnt, 0, N * sizeof(int), stream);
    hist_kernel<<<640, 256, 0, stream>>>(row, cnt, E);
    scan_kernel<<<1, 1024, 0, stream>>>(cnt, off, cur, N);
    node_pre8<<<(N + 7) / 8, 512, 0, stream>>>(
        h, W, bias, att_w1, att_b1, Xrow, XQh, Pbuf, row, col, edge_attr,
        edge_mask, cur, rec, N, E);
    edge_agg<<<(N + 1) / 2, 256, 0, stream>>>(Xrow, Pbuf, XQh, rec, off, cnt,
                                              att_w1 + 256 * D, att_w2,
                                              att_b2, aggP, N);
    node_post<<<(N + 15) / 16, 256, 0, stream>>>(Xrow, aggP, ln_g, ln_b,
                                                 (float*)d_out, N);
}

// Round 14
// 136.792 us; speedup vs baseline: 1.0704x; 1.0247x over previous
//
#include <hip/hip_runtime.h>
#include <hip/hip_fp16.h>
#include <math.h>

#define D 128
#define EPS1 (1.0f + 1e-6f)

// ---- DPP row_ror sum over each 16-lane row: all lanes get the total ----
__device__ __forceinline__ float dpp_rsum16(float v) {
    v += __int_as_float(__builtin_amdgcn_update_dpp(
        0, __float_as_int(v), 0x121, 0xf, 0xf, true));  // ror:1
    v += __int_as_float(__builtin_amdgcn_update_dpp(
        0, __float_as_int(v), 0x122, 0xf, 0xf, true));  // ror:2
    v += __int_as_float(__builtin_amdgcn_update_dpp(
        0, __float_as_int(v), 0x124, 0xf, 0xf, true));  // ror:4
    v += __int_as_float(__builtin_amdgcn_update_dpp(
        0, __float_as_int(v), 0x128, 0xf, 0xf, true));  // ror:8
    return v;
}

// full 64-lane sum, all lanes get the total
__device__ __forceinline__ float wsum64(float v) {
    v = dpp_rsum16(v);
    v += __shfl_xor(v, 16, 64);
    v += __shfl_xor(v, 32, 64);
    return v;
}

// fast acosh for a >= 1+1e-6
__device__ __forceinline__ float facosh(float a) {
    return __logf(a + sqrtf(fmaxf(a * a - 1.0f, 0.0f)));
}

__device__ __forceinline__ void unpack8(const float4& a, const float4& b,
                                        float* d) {
    d[0] = a.x; d[1] = a.y; d[2] = a.z; d[3] = a.w;
    d[4] = b.x; d[5] = b.y; d[6] = b.z; d[7] = b.w;
}

// 8 halfs packed in a float4 -> 8 floats
__device__ __forceinline__ void unpackh8(const float4& v, float* d) {
    const __half2* p = (const __half2*)&v;
#pragma unroll
    for (int t = 0; t < 4; t++) {
        float2 f = __half22float2(p[t]);
        d[2 * t] = f.x;
        d[2 * t + 1] = f.y;
    }
}

// ---------------------------------------------------------------------------
// hist: grid-stride histogram of row into cnt
// ---------------------------------------------------------------------------
__global__ void hist_kernel(const int* __restrict__ row, int* __restrict__ cnt,
                            int E) {
    for (int e = blockIdx.x * blockDim.x + threadIdx.x; e < E;
         e += gridDim.x * blockDim.x)
        atomicAdd(&cnt[row[e]], 1);
}

// ---------------------------------------------------------------------------
// scan: one-pass single-block exclusive scan
// ---------------------------------------------------------------------------
__global__ __launch_bounds__(1024) void scan_kernel(const int* __restrict__ cnt,
                                                    int* __restrict__ off,
                                                    int* __restrict__ cursor,
                                                    int N) {
    __shared__ int wt[16];
    int tid = threadIdx.x, lane = tid & 63, wid = tid >> 6;
    int PER = (N + 1023) >> 10;
    int basei = tid * PER;
    int loc[16];
    int tsum = 0;
#pragma unroll 4
    for (int r = 0; r < PER; r++) {
        int idx = basei + r;
        int v = (idx < N) ? cnt[idx] : 0;
        loc[r] = tsum;
        tsum += v;
    }
    int inc = tsum;
#pragma unroll
    for (int o = 1; o < 64; o <<= 1) {
        int t = __shfl_up(inc, o, 64);
        if (lane >= o) inc += t;
    }
    if (lane == 63) wt[wid] = inc;
    __syncthreads();
    if (tid < 16) {
        int w = wt[tid];
#pragma unroll
        for (int o = 1; o < 16; o <<= 1) {
            int t = __shfl_up(w, o, 64);
            if ((tid & 15) >= o) w += t;
        }
        wt[tid] = w;
    }
    __syncthreads();
    int wbase = (wid == 0) ? 0 : wt[wid - 1];
    int texcl = wbase + inc - tsum;
    for (int r = 0; r < PER; r++) {
        int idx = basei + r;
        if (idx < N) {
            int o = texcl + loc[r];
            off[idx] = o;
            cursor[idx] = o;
        }
    }
}

// ---------------------------------------------------------------------------
// Kernel 1 v3 (R13, unchanged): per-node pre-processing, 4 barriers.
// 512 threads = 8 waves; wave wv owns node i0+wv. Matmuls k-split via LDS
// psum; elementwise wave-local with DPP reductions. Tail: grid-stride
// scatter (cursor ready: scan runs before this kernel).
// ---------------------------------------------------------------------------
__global__ __launch_bounds__(512) void node_pre8(
    const float* __restrict__ h, const float* __restrict__ W,
    const float* __restrict__ bias, const float* __restrict__ att_w1,
    const float* __restrict__ att_b1, float* __restrict__ Xrow,
    __half* __restrict__ XQh, float* __restrict__ P_out,
    const int* __restrict__ row, const int* __restrict__ col,
    const float* __restrict__ edge_attr, const float* __restrict__ edge_mask,
    int* __restrict__ cursor, float4* __restrict__ rec, int N, int E) {
    int i0 = blockIdx.x * 8;
    int tid = threadIdx.x;
    int j = tid & 127, kp = tid >> 7;
    int lane = tid & 63, wv = tid >> 6;
    int j0 = 2 * lane;
    __shared__ __align__(16) float t8[8][D];
    __shared__ float psP[4][8][D];
    __shared__ float psQ[4][8][D];

    bool vA = (i0 + wv) < N;
    size_t gA = min(i0 + wv, N - 1);

    // ---- Phase A: logmap0(h) -> t8[wv] ----
    float2 hA = *(const float2*)&h[gA * D + j0];
    float h0A = fmaxf(__shfl(hA.x, 0, 64), EPS1);
    float facA = facosh(h0A) * rsqrtf(h0A * h0A - 1.0f);
    float tax = (lane == 0) ? 0.0f : hA.x * facA;
    float tay = hA.y * facA;
    *(float2*)&t8[wv][j0] = make_float2(tax, tay);
    __syncthreads();  // B1

    // ---- Phase B: xt partials ----
    {
        float xtp[8];
#pragma unroll
        for (int n = 0; n < 8; n++) xtp[n] = 0.0f;
        int kbeg = kp * 32;
        for (int k0 = kbeg; k0 < kbeg + 32; k0 += 4) {
            float w0 = W[(k0 + 0) * D + j], w1 = W[(k0 + 1) * D + j];
            float w2 = W[(k0 + 2) * D + j], w3 = W[(k0 + 3) * D + j];
#pragma unroll
            for (int n = 0; n < 8; n++) {
                float4 tv = *(const float4*)&t8[n][k0];
                xtp[n] = fmaf(
                    tv.x, w0,
                    fmaf(tv.y, w1, fmaf(tv.z, w2, fmaf(tv.w, w3, xtp[n]))));
            }
        }
#pragma unroll
        for (int n = 0; n < 8; n++) psP[kp][n][j] = xtp[n];
    }
    __syncthreads();  // B2

    // ---- Phase C: wave-local elementwise chain ----
    float xnax, xnay;
    {
        float2 a0 = *(const float2*)&psP[0][wv][j0];
        float2 a1 = *(const float2*)&psP[1][wv][j0];
        float2 a2 = *(const float2*)&psP[2][wv][j0];
        float2 a3 = *(const float2*)&psP[3][wv][j0];
        float xtax = a0.x + a1.x + a2.x + a3.x;
        float xtay = a0.y + a1.y + a2.y + a3.y;
        if (lane == 0) xtax = 0.0f;

        float nsqA = wsum64(xtax * xtax + xtay * xtay);
        float nnA = sqrtf(fmaxf(nsqA, 1e-6f));
        float eA = __expf(nnA), eiA = __fdividef(1.0f, eA);
        float chA = 0.5f * (eA + eiA), shA = __fdividef(0.5f * (eA - eiA), nnA);
        float xax = (lane == 0) ? chA : shA * xtax;
        float xay = shA * xtay;

        float2 bv = *(const float2*)&bias[j0];
        float va = (lane == 0) ? 0.0f : bv.x, vb = bv.y;
        float lxvA = wsum64(xax * va + xay * vb);
        float coefA = __fdividef(lxvA, 1.0f + chA);
        float baA = (lane == 0) ? coefA * (chA + 1.0f) : fmaf(coefA, xax, va);
        float bbA = fmaf(coefA, xay, vb);
        float lbbA = wsum64(((lane == 0) ? -baA * baA : baA * baA) + bbA * bbA);
        float nbA = sqrtf(fmaxf(lbbA, 1e-6f));
        float e2A = __expf(nbA), ei2A = __fdividef(1.0f, e2A);
        float ch2A = 0.5f * (e2A + ei2A);
        float sh2A = __fdividef(0.5f * (e2A - ei2A), nbA);
        xnax = ch2A * xax + sh2A * baA;
        xnay = ch2A * xay + sh2A * bbA;
        if (vA) {
            *(float2*)&Xrow[gA * D + j0] = make_float2(xnax, xnay);
            *(__half2*)&XQh[gA * 256 + j0] =
                __float22half2_rn(make_float2(xnax, xnay));
        }

        float Y0A = fmaxf(__shfl(xnax, 0, 64), EPS1);
        float fA = facosh(Y0A) * rsqrtf(Y0A * Y0A - 1.0f);
        float x2ax = (lane == 0) ? 0.0f : xnax * fA;
        float x2ay = xnay * fA;
        *(float2*)&t8[wv][j0] = make_float2(x2ax, x2ay);
    }
    __syncthreads();  // B3

    // ---- Phase D: P/Q partials ----
    {
        float pp[8], qq[8];
#pragma unroll
        for (int n = 0; n < 8; n++) {
            pp[n] = 0.0f;
            qq[n] = 0.0f;
        }
        int kbeg = kp * 32;
        for (int k0 = kbeg; k0 < kbeg + 32; k0 += 4) {
            float a0 = att_w1[(k0 + 0) * D + j], a1 = att_w1[(k0 + 1) * D + j];
            float a2 = att_w1[(k0 + 2) * D + j], a3 = att_w1[(k0 + 3) * D + j];
            float c0 = att_w1[(D + k0 + 0) * D + j];
            float c1 = att_w1[(D + k0 + 1) * D + j];
            float c2 = att_w1[(D + k0 + 2) * D + j];
            float c3 = att_w1[(D + k0 + 3) * D + j];
#pragma unroll
            for (int n = 0; n < 8; n++) {
                float4 tv = *(const float4*)&t8[n][k0];
                pp[n] = fmaf(
                    tv.x, a0,
                    fmaf(tv.y, a1, fmaf(tv.z, a2, fmaf(tv.w, a3, pp[n]))));
                qq[n] = fmaf(
                    tv.x, c0,
                    fmaf(tv.y, c1, fmaf(tv.z, c2, fmaf(tv.w, c3, qq[n]))));
            }
        }
#pragma unroll
        for (int n = 0; n < 8; n++) {
            psP[kp][n][j] = pp[n];
            psQ[kp][n][j] = qq[n];
        }
    }
    __syncthreads();  // B4

    // ---- Phase E: assembly + stores ----
    if (vA) {
        float2 b1v = *(const float2*)&att_b1[j0];
        float2 a0 = *(const float2*)&psP[0][wv][j0];
        float2 a1 = *(const float2*)&psP[1][wv][j0];
        float2 a2 = *(const float2*)&psP[2][wv][j0];
        float2 a3 = *(const float2*)&psP[3][wv][j0];
        float2 q0 = *(const float2*)&psQ[0][wv][j0];
        float2 q1 = *(const float2*)&psQ[1][wv][j0];
        float2 q2 = *(const float2*)&psQ[2][wv][j0];
        float2 q3 = *(const float2*)&psQ[3][wv][j0];
        *(float2*)&P_out[gA * D + j0] =
            make_float2(a0.x + a1.x + a2.x + a3.x + b1v.x,
                        a0.y + a1.y + a2.y + a3.y + b1v.y);
        *(__half2*)&XQh[gA * 256 + 128 + j0] = __float22half2_rn(
            make_float2(q0.x + q1.x + q2.x + q3.x, q0.y + q1.y + q2.y + q3.y));
    }

    // ---- Tail: grid-stride scatter ----
    const float2* ea2 = (const float2*)edge_attr;
    int gtid = blockIdx.x * 512 + tid;
    int tot = gridDim.x * 512;
    for (int e = gtid; e < E; e += tot) {
        int r = row[e];
        int pos = atomicAdd(&cursor[r], 1);
        float2 a = ea2[e];
        rec[pos] = make_float4(__int_as_float(col[e]), a.x, a.y, edge_mask[e]);
    }
}

// ---------------------------------------------------------------------------
// Kernel D: edge aggregation + FUSED epilogue. Block = 4 waves = 2 nodes;
// waves {0,1} own node A, {2,3} node B. Per wave: 4 chunks (8 chunks/node);
// rec preloaded to lane registers; gathers 2 computes ahead. Wave partials
// merge through 2 KB LDS + ONE barrier; wave 0/2 runs register epilogue.
// ---------------------------------------------------------------------------
__global__ __launch_bounds__(256) void edge_agg(
    const float* __restrict__ Xrow, const float* __restrict__ P,
    const __half* __restrict__ XQh, const float4* __restrict__ rec,
    const int* __restrict__ off, const int* __restrict__ cnt,
    const float* __restrict__ w1c, const float* __restrict__ att_w2,
    const float* __restrict__ att_b2, const float* __restrict__ gamma,
    const float* __restrict__ beta, float* __restrict__ out, int N) {
    int tid = threadIdx.x, lane = tid & 63, wid = tid >> 6;
    int sub = lane & 15, grp = lane >> 4, gb = lane & 48;
    int i = blockIdx.x * 2 + (wid >> 1);
    int w = wid & 1;
    bool valid = i < N;
    i = min(i, N - 1);
    int j8 = sub * 8, f4 = sub * 2;
    __shared__ __align__(16) float part[4][D];  // 2 KB wave partials

    const float4* w4 = (const float4*)w1c;
    const float4* aw4 = (const float4*)att_w2;
    const float4* xr4 = (const float4*)(Xrow + (size_t)i * D);
    const float4* pr4 = (const float4*)(P + (size_t)i * D);
    float xr[8], pr[8], wa[8], wb[8], wg[8], w2v[8];
    unpack8(xr4[f4], xr4[f4 + 1], xr);
    unpack8(pr4[f4], pr4[f4 + 1], pr);
    unpack8(w4[f4], w4[f4 + 1], wa);
    unpack8(w4[32 + f4], w4[32 + f4 + 1], wb);
    unpack8(w4[64 + f4], w4[64 + f4 + 1], wg);
    unpack8(aw4[f4], aw4[f4 + 1], w2v);
    float b2 = att_b2[0];
    float xr0s = (sub == 0) ? -xr[0] : xr[0];

    float acc[8];
#pragma unroll
    for (int u = 0; u < 8; u++) acc[u] = 0.0f;

    int s = off[i], m = valid ? cnt[i] : 0;
    int clen = (m + 7) >> 3;
    int base = (w * 4 + grp) * clen;
    int len = min(m - base, clen);
    if (len < 0) len = 0;

    float4 rp = make_float4(__int_as_float(0), 0.0f, 0.0f, 0.0f);
    if (sub < len) rp = rec[s + base + sub];
    int colp = __float_as_int(rp.x);

    auto computeE = [&](float eay, float eaz, float msk, bool act,
                        const float4& g0, const float4& g1) {
        float xc[8], qc[8];
        unpackh8(g0, xc);
        unpackh8(g1, qc);
        float lin = xr0s * xc[0];
#pragma unroll
        for (int u = 1; u < 8; u++) lin = fmaf(xr[u], xc[u], lin);
        lin = dpp_rsum16(lin);
        float alpha = fmaxf(-lin, EPS1);
        float a2m = fmaxf(fmaf(alpha, alpha, -1.0f), 1e-12f);
        float rden = rsqrtf(a2m);
        float geo = __logf(fmaf(a2m, rden, alpha));
        float lp = 0.0f;
#pragma unroll
        for (int u = 0; u < 8; u++) {
            float hv = pr[u] + qc[u] +
                       fmaf(eay, wa[u], fmaf(eaz, wb[u], geo * wg[u]));
            float sig = __fdividef(1.0f, 1.0f + __expf(-hv));
            lp = fmaf(hv * sig, w2v[u], lp);
        }
        lp = dpp_rsum16(lp);
        float wq = act ? msk : 0.0f;
        float att = wq * __fdividef(1.0f, 1.0f + __expf(-(lp + b2)));
        float scale = att * geo * rden * 1e-3f;
#pragma unroll
        for (int u = 0; u < 8; u++)
            acc[u] = fmaf(scale, fmaf(-alpha, xr[u], xc[u]), acc[u]);
    };

    int tmax = min(clen, 16);
    {
        int c0 = __shfl(colp, gb | 0, 64);
        const float4* p0 = (const float4*)(XQh + (size_t)c0 * 256);
        float4 gA0 = p0[sub], gA1 = p0[16 + sub];
        int c1 = __shfl(colp, gb | 1, 64);
        const float4* p1 = (const float4*)(XQh + (size_t)c1 * 256);
        float4 gB0 = p1[sub], gB1 = p1[16 + sub];
        float4 gC0, gC1;

        for (int t = 0; t < tmax; ++t) {
            int cn = __shfl(colp, gb | ((t + 2) & 15), 64);
            const float4* pn = (const float4*)(XQh + (size_t)cn * 256);
            gC0 = pn[sub];
            gC1 = pn[16 + sub];
            float eay = __shfl(rp.y, gb | t, 64);
            float eaz = __shfl(rp.z, gb | t, 64);
            float msk = __shfl(rp.w, gb | t, 64);
            computeE(eay, eaz, msk, t < len, gA0, gA1);
            gA0 = gB0; gA1 = gB1;
            gB0 = gC0; gB1 = gC1;
        }
    }
    for (int t = 16; t < clen; ++t) {
        bool act = t < len;
        float4 rc = make_float4(__int_as_float(0), 0.0f, 0.0f, 0.0f);
        if (act) rc = rec[s + base + t];
        const float4* pt =
            (const float4*)(XQh + (size_t)__float_as_int(rc.x) * 256);
        float4 g0 = pt[sub], g1 = pt[16 + sub];
        computeE(rc.y, rc.z, rc.w, act, g0, g1);
    }

    // merge this wave's 4 chunk-partials; grp 0 writes wave partial to LDS
#pragma unroll
    for (int u = 0; u < 8; u++) {
        acc[u] += __shfl_xor(acc[u], 16, 64);
        acc[u] += __shfl_xor(acc[u], 32, 64);
    }
    if (grp == 0) {
        *(float4*)&part[wid][j8] = make_float4(acc[0], acc[1], acc[2], acc[3]);
        *(float4*)&part[wid][j8 + 4] =
            make_float4(acc[4], acc[5], acc[6], acc[7]);
    }
    __syncthreads();

    // ---- fused epilogue: wave 0 (node A) / wave 2 (node B) only ----
    if (w != 0 || !valid) return;
    {
        float4 pa0 = *(const float4*)&part[wid][j8];
        float4 pa1 = *(const float4*)&part[wid][j8 + 4];
        float4 pb0 = *(const float4*)&part[wid + 1][j8];
        float4 pb1 = *(const float4*)&part[wid + 1][j8 + 4];
        acc[0] = pa0.x + pb0.x; acc[1] = pa0.y + pb0.y;
        acc[2] = pa0.z + pb0.z; acc[3] = pa0.w + pb0.w;
        acc[4] = pa1.x + pb1.x; acc[5] = pa1.y + pb1.y;
        acc[6] = pa1.z + pb1.z; acc[7] = pa1.w + pb1.w;
    }

    float lxa_p = (sub == 0) ? -xr[0] * acc[0] : xr[0] * acc[0];
#pragma unroll
    for (int u = 1; u < 8; u++) lxa_p = fmaf(xr[u], acc[u], lxa_p);
    float lxa = dpp_rsum16(lxa_p);
    float uj[8];
#pragma unroll
    for (int u = 0; u < 8; u++) uj[u] = fmaf(lxa, xr[u], acc[u]);
    float luu_p = (sub == 0) ? -uj[0] * uj[0] : uj[0] * uj[0];
#pragma unroll
    for (int u = 1; u < 8; u++) luu_p = fmaf(uj[u], uj[u], luu_p);
    float luu = dpp_rsum16(luu_p);
    float nn = sqrtf(fmaxf(luu, 1e-6f));
    float e = __expf(nn), ei = __fdividef(1.0f, e);
    float ch = 0.5f * (e + ei), shv = __fdividef(0.5f * (e - ei), nn);
    float xn[8];
#pragma unroll
    for (int u = 0; u < 8; u++) xn[u] = ch * xr[u] + shv * uj[u];
    float X0 = __shfl(xn[0], lane & 48, 64);
    X0 = fmaxf(X0, EPS1);
    float fc = facosh(X0) * rsqrtf(X0 * X0 - 1.0f);
    float ht[8];
#pragma unroll
    for (int u = 0; u < 8; u++) ht[u] = xn[u] * fc;
    if (sub == 0) ht[0] = 0.0f;
    float mp = 0.0f;
#pragma unroll
    for (int u = 0; u < 8; u++) mp += ht[u];
    float mean = dpp_rsum16(mp) * (1.0f / 127.0f);
    float diff[8];
#pragma unroll
    for (int u = 0; u < 8; u++) diff[u] = ht[u] - mean;
    if (sub == 0) diff[0] = 0.0f;
    float vp = 0.0f;
#pragma unroll
    for (int u = 0; u < 8; u++) vp = fmaf(diff[u], diff[u], vp);
    float var = dpp_rsum16(vp) * (1.0f / 127.0f);
    float rstd = rsqrtf(var + 1e-5f);
    float sp[8];
#pragma unroll
    for (int u = 0; u < 8; u++) {
        int jj = j8 + u;
        float g = (jj > 0) ? gamma[jj - 1] : 0.0f;
        float bt = (jj > 0) ? beta[jj - 1] : 0.0f;
        sp[u] = fmaf(diff[u] * rstd, g, bt);
    }
    if (sub == 0) sp[0] = 0.0f;
    float n2p = 0.0f;
#pragma unroll
    for (int u = 0; u < 8; u++) n2p = fmaf(sp[u], sp[u], n2p);
    float n2 = sqrtf(fmaxf(dpp_rsum16(n2p), 1e-6f));
    e = __expf(n2);
    ei = __fdividef(1.0f, e);
    float y0 = 0.5f * (e + ei), sh2 = __fdividef(0.5f * (e - ei), n2);
    float yj[8];
#pragma unroll
    for (int u = 0; u < 8; u++) yj[u] = sh2 * sp[u];
    if (sub == 0) yj[0] = y0;
    float y0c = fmaxf(y0, EPS1);
    float f3 = facosh(y0c) * rsqrtf(y0c * y0c - 1.0f);
    float sj[8];
#pragma unroll
    for (int u = 0; u < 8; u++) {
        float lj = yj[u] * f3;
        sj[u] = __fdividef(lj, 1.0f + __expf(-lj));
    }
    if (sub == 0) sj[0] = 0.0f;
    float n3p = 0.0f;
#pragma unroll
    for (int u = 0; u < 8; u++) n3p = fmaf(sj[u], sj[u], n3p);
    float n3 = sqrtf(fmaxf(dpp_rsum16(n3p), 1e-6f));
    e = __expf(n3);
    ei = __fdividef(1.0f, e);
    float o0 = 0.5f * (e + ei), sh3 = __fdividef(0.5f * (e - ei), n3);
    float ov[8];
#pragma unroll
    for (int u = 0; u < 8; u++) ov[u] = sh3 * sj[u];
    if (sub == 0) ov[0] = o0;
    if (grp == 0) {
        float4* o4 = (float4*)(out + (size_t)i * D);
        o4[f4] = make_float4(ov[0], ov[1], ov[2], ov[3]);
        o4[f4 + 1] = make_float4(ov[4], ov[5], ov[6], ov[7]);
    }
}

extern "C" void kernel_launch(void* const* d_in, const int* in_sizes, int n_in,
                              void* d_out, int out_size, void* d_ws,
                              size_t ws_size, hipStream_t stream) {
    const float* h = (const float*)d_in[0];
    const float* edge_attr = (const float*)d_in[1];
    const int* row = (const int*)d_in[2];
    const int* col = (const int*)d_in[3];
    const float* edge_mask = (const float*)d_in[5];
    const float* W = (const float*)d_in[6];
    const float* bias = (const float*)d_in[7];
    const float* att_w1 = (const float*)d_in[8];
    const float* att_b1 = (const float*)d_in[9];
    const float* att_w2 = (const float*)d_in[10];
    const float* att_b2 = (const float*)d_in[11];
    const float* ln_g = (const float*)d_in[12];
    const float* ln_b = (const float*)d_in[13];

    int N = in_sizes[0] / D;
    int E = in_sizes[2];

    float* Xrow = (float*)d_ws;                      // N*128 fp32
    float* Pbuf = Xrow + (size_t)N * D;              // N*128 fp32
    __half* XQh = (__half*)(Pbuf + (size_t)N * D);   // N*256 fp16
    float4* rec = (float4*)(XQh + (size_t)N * 256);  // E recs
    int* cnt = (int*)(rec + E);
    int* off = cnt + N;
    int* cur = off + N;

    hipMemsetAsync(cnt, 0, N * sizeof(int), stream);
    hist_kernel<<<640, 256, 0, stream>>>(row, cnt, E);
    scan_kernel<<<1, 1024, 0, stream>>>(cnt, off, cur, N);
    node_pre8<<<(N + 7) / 8, 512, 0, stream>>>(
        h, W, bias, att_w1, att_b1, Xrow, XQh, Pbuf, row, col, edge_attr,
        edge_mask, cur, rec, N, E);
    edge_agg<<<(N + 1) / 2, 256, 0, stream>>>(
        Xrow, Pbuf, XQh, rec, off, cnt, att_w1 + 256 * D, att_w2, att_b2,
        ln_g, ln_b, (float*)d_out, N);
}